// Round 11
// baseline (485.382 us; speedup 1.0000x reference)
//
#include <hip/hip_runtime.h>
#include <stdint.h>

#define NBATCH 16384
#define TT     20
#define CC     256
#define FP     260   // f32 LDS row stride (1040B): rows shift 4 banks -> 2-way (free) on b128
#define FB     520   // bf16 row stride in u16 within same row slot (bytes reused in place)
#define LDK    264   // sT row stride (u16)
#define TP     40    // sVT inner stride (u16)
#define NT     256   // 4 waves

typedef __bf16 bf16x8 __attribute__((ext_vector_type(8)));
typedef float  f32x4  __attribute__((ext_vector_type(4)));

#define GLL16(g, l) __builtin_amdgcn_global_load_lds( \
    (const __attribute__((address_space(1))) uint32_t*)(g), \
    (__attribute__((address_space(3))) uint32_t*)(l), 16, 0, 0)

// vm+lgkm drain barrier (stage); lgkm-only barrier (LDS phases — global prefetch stays in flight)
#define BAR_VM()   do { asm volatile("s_waitcnt vmcnt(0) lgkmcnt(0)" ::: "memory"); \
                        __builtin_amdgcn_s_barrier(); } while (0)
#define BAR_LGKM() do { asm volatile("s_waitcnt lgkmcnt(0)" ::: "memory"); \
                        __builtin_amdgcn_s_barrier(); } while (0)

// tb_mask tables: t=0,1:{0,1,2} t=2:{0,1,2,3} t=3..15:{t,t+1} t=16:uniform t=17..19:{17,18,19}
__constant__ int8_t c_CNT[TT] = {3,3,4,2,2,2,2,2,2,2,2,2,2,2,2,2,0,3,3,3};
__constant__ int8_t c_OFF[TT] = {0,3,6,10,12,14,16,18,20,22,24,26,28,30,32,34,0,36,39,42};
__constant__ int8_t c_PT[45]  = {0,0,0,1,1,1,2,2,2,2,3,3,4,4,5,5,6,6,7,7,8,8,9,9,
                                 10,10,11,11,12,12,13,13,14,14,15,15,17,17,17,18,18,18,19,19,19};
__constant__ int8_t c_PS[45]  = {0,1,2,0,1,2,0,1,2,3,3,4,4,5,5,6,6,7,7,8,8,9,9,10,
                                 10,11,11,12,12,13,13,14,14,15,15,16,17,18,19,17,18,19,17,18,19};

__device__ __forceinline__ uint16_t f2bf(float f) {
    __bf16 b = (__bf16)f;
    return __builtin_bit_cast(uint16_t, b);
}
__device__ __forceinline__ uint32_t pk2(float a, float b) {
    return (uint32_t)f2bf(a) | ((uint32_t)f2bf(b) << 16);
}
__device__ __forceinline__ float bflo(uint32_t u) { return __builtin_bit_cast(float, u << 16); }
__device__ __forceinline__ float bfhi(uint32_t u) { return __builtin_bit_cast(float, u & 0xffff0000u); }

// prep1: mqkT[n][k] = sum_h Wk[h,n]*Wq[h,k] / 16 ;  wvb[n][k] = bf16(Wv[n][k])
__global__ void prep1_kernel(const float* __restrict__ Wq, const float* __restrict__ Wk,
                             const float* __restrict__ Wv, uint16_t* __restrict__ mqkT,
                             uint16_t* __restrict__ wvb) {
    const int n = blockIdx.x;
    const int k = threadIdx.x;
    float acc = 0.f;
    for (int h = 0; h < CC; ++h)
        acc = fmaf(Wk[h * CC + n], Wq[h * CC + k], acc);
    mqkT[n * CC + k] = f2bf(acc * 0.0625f);
    wvb[n * CC + k]  = f2bf(Wv[n * CC + k]);
}

// prep2: swizzle tables into per-wave MFMA fragment order (one coalesced 1KB load per frag)
__global__ void prep2_kernel(const uint16_t* __restrict__ mqkT, const uint16_t* __restrict__ wvb,
                             uint16_t* __restrict__ BqS, uint16_t* __restrict__ BvS) {
    const int bid = blockIdx.x;          // 0..63 : m*32 + w*8 + kk
    const int m  = bid >> 5;
    const int w  = (bid >> 3) & 3;
    const int kk = bid & 7;
    const int ct   = threadIdx.x >> 6;
    const int lane = threadIdx.x & 63;
    const uint16_t* src = m ? wvb : mqkT;
    uint16_t*       dst = m ? BvS : BqS;
    const int n   = w * 64 + ct * 16 + (lane & 15);
    const int col = kk * 32 + ((lane >> 4) << 3);
    uint4 v = *(const uint4*)(src + n * CC + col);
    *(uint4*)(dst + ((size_t)((w * 32 + kk * 4 + ct) * 64 + lane) << 3)) = v;
}

// bf16 fragment: single b128 from in-place-converted row r, 8-elem unit u
__device__ __forceinline__ bf16x8 ldb(const uint16_t* __restrict__ s, int r, int u) {
    return __builtin_bit_cast(bf16x8, *(const uint4*)(s + r * FB + (u << 3)));
}

__global__ __launch_bounds__(NT, 3)
void attn_main(const float* __restrict__ f1g, const float* __restrict__ f2g,
               const uint16_t* __restrict__ BqS, const uint16_t* __restrict__ BvS,
               float* __restrict__ outg) {
    __shared__ char smem[54400];
    float*    sF1f  = (float*)smem;                   // feat1 f32 (20*1040B); bf16 in place
    float*    sF2f  = (float*)(smem + 20800);         // feat2 f32
    uint16_t* sT    = (uint16_t*)(smem + 41600);      // t1 bf16 [t][h], 10560B
    uint16_t* attnL = (uint16_t*)(smem + 52160);      // 32x32 exp-weights, 2048B
    float*    s_simE = (float*)(smem + 54208);        // 45 f32
    uint16_t* sFb1 = (uint16_t*)sF1f;                 // bf16 view, stride FB
    uint16_t* sFb2 = (uint16_t*)sF2f;
    uint16_t* sVT  = (uint16_t*)smem;                 // v^T [256][TP] overlays sF1 after B2

    const int tid  = threadIdx.x;
    const int lane = tid & 63;
    const int w    = tid >> 6;             // wave owns 64 hid cols
    const int l15  = lane & 15;
    const int q    = lane >> 4;
    const size_t base = (size_t)blockIdx.x * TT * CC;
    const float* f1 = f1g + base;
    const float* f2 = f2g + base;

    // ---- stage: async DMA fp32 rows -> LDS (zero VGPR, zero VALU) ----
#pragma unroll
    for (int j = 0; j < 5; ++j) {
        int r = w * 5 + j;
        GLL16(f1 + r * 256 + (lane << 2), sF1f + r * FP);
        GLL16(f2 + r * 256 + (lane << 2), sF2f + r * FP);
    }
    {   // attnL prefill: zeros; row16 cols0..19 = 1.0 (uniform-row trick)
        uint32_t* aL = (uint32_t*)attnL;
#pragma unroll
        for (int rep = 0; rep < 2; ++rep) {
            int s = tid + (rep << 8);
            aL[s] = ((s >> 4) == 16 && (s & 15) < 10) ? 0x3F803F80u : 0u;
        }
    }
    BAR_VM();                              // B1: DMA complete

    // ---- convert-once: f32 -> bf16 in place; wave-owned rows => no cross-wave hazard ----
#pragma unroll
    for (int j = 0; j < 5; ++j) {
        int r = w * 5 + j;
        float4 v1 = *(const float4*)(sF1f + r * FP + (lane << 2));
        float4 v2 = *(const float4*)(sF2f + r * FP + (lane << 2));
        uint2 u1; u1.x = pk2(v1.x, v1.y); u1.y = pk2(v1.z, v1.w);
        uint2 u2; u2.x = pk2(v2.x, v2.y); u2.y = pk2(v2.z, v2.w);
        *(uint2*)(sFb1 + r * FB + (lane << 2)) = u1;
        *(uint2*)(sFb2 + r * FB + (lane << 2)) = u2;
    }
    BAR_LGKM();                            // B1.5: bf16 tiles visible

    const uint16_t* bq = BqS + ((size_t)w << 14);
    const uint16_t* bv = BvS + ((size_t)w << 14);
    const int rB0 = l15;
    const int rB1 = (16 + l15 < TT) ? 16 + l15 : TT - 1;

    // ---- phase A: GEMM1 swapped (A=Mqk frags, B=feat1^T) -> t1^T -> sT ----
    {
        f32x4 acc[4][2];
#pragma unroll
        for (int mt = 0; mt < 4; ++mt)
#pragma unroll
            for (int ct = 0; ct < 2; ++ct)
                acc[mt][ct] = f32x4{0.f, 0.f, 0.f, 0.f};
        __builtin_amdgcn_s_setprio(1);
#pragma unroll
        for (int kk = 0; kk < 8; ++kk) {
            const int u = (kk << 2) + q;
            bf16x8 b0 = ldb(sFb1, rB0, u);
            bf16x8 b1 = ldb(sFb1, rB1, u);
#pragma unroll
            for (int mt = 0; mt < 4; ++mt) {
                bf16x8 am = __builtin_bit_cast(bf16x8,
                    *(const uint4*)(bq + (((kk << 2) + mt) * 64 + lane) * 8));
                acc[mt][0] = __builtin_amdgcn_mfma_f32_16x16x32_bf16(am, b0, acc[mt][0], 0, 0, 0);
                acc[mt][1] = __builtin_amdgcn_mfma_f32_16x16x32_bf16(am, b1, acc[mt][1], 0, 0, 0);
            }
        }
        __builtin_amdgcn_s_setprio(0);
        // D: lane holds t1^T[h = w*64+mt*16+4q+j][t = ct*16+l15] -> sT[t][h]
#pragma unroll
        for (int mt = 0; mt < 4; ++mt)
#pragma unroll
            for (int ct = 0; ct < 2; ++ct) {
                int t = ct * 16 + l15;
                if (t < TT) {
                    int h0 = (w << 6) + mt * 16 + (q << 2);
                    uint2 u2;
                    u2.x = pk2(acc[mt][ct][0], acc[mt][ct][1]);
                    u2.y = pk2(acc[mt][ct][2], acc[mt][ct][3]);
                    *(uint2*)&sT[t * LDK + h0] = u2;
                }
            }
    }
    BAR_LGKM();                            // B2: sT visible; sFb1 reads done

    // ---- phase B: sim+exp (180 thr) then GEMM2 -> sVT (overlays sF1 region) ----
    if (tid < 180) {
        int d = tid >> 2, p = tid & 2 * 2 - 1 & 3;
        p = tid & 3;
        int t = c_PT[d], s = c_PS[d];
        const uint16_t* ap = sT + t * LDK + (p << 3);
        const uint16_t* bp = sFb2 + s * FB + (p << 3);
        float da = 0.f;
#pragma unroll
        for (int c = 0; c < 256; c += 32) {   // h = p*8 + c .. +8
            uint4 ua = *(const uint4*)(ap + c);
            uint4 ub = *(const uint4*)(bp + c);
            da = fmaf(bflo(ua.x), bflo(ub.x), da);
            da = fmaf(bfhi(ua.x), bfhi(ub.x), da);
            da = fmaf(bflo(ua.y), bflo(ub.y), da);
            da = fmaf(bfhi(ua.y), bfhi(ub.y), da);
            da = fmaf(bflo(ua.z), bflo(ub.z), da);
            da = fmaf(bfhi(ua.z), bfhi(ub.z), da);
            da = fmaf(bflo(ua.w), bflo(ub.w), da);
            da = fmaf(bfhi(ua.w), bfhi(ub.w), da);
        }
        da += __shfl_xor(da, 1);
        da += __shfl_xor(da, 2);
        if (p == 0) {
            float e = __expf(da);
            attnL[t * 32 + s] = f2bf(e);
            s_simE[d] = e;
        }
    }
    {
        f32x4 av[2][4];
#pragma unroll
        for (int rt = 0; rt < 2; ++rt)
#pragma unroll
            for (int ct = 0; ct < 4; ++ct)
                av[rt][ct] = f32x4{0.f, 0.f, 0.f, 0.f};
        __builtin_amdgcn_s_setprio(1);
#pragma unroll
        for (int kk = 0; kk < 8; ++kk) {
            const int u = (kk << 2) + q;
            bf16x8 a0 = ldb(sFb2, rB0, u);
            bf16x8 a1 = ldb(sFb2, rB1, u);
#pragma unroll
            for (int ct = 0; ct < 4; ++ct) {
                bf16x8 bm = __builtin_bit_cast(bf16x8,
                    *(const uint4*)(bv + (((kk << 2) + ct) * 64 + lane) * 8));
                av[0][ct] = __builtin_amdgcn_mfma_f32_16x16x32_bf16(a0, bm, av[0][ct], 0, 0, 0);
                av[1][ct] = __builtin_amdgcn_mfma_f32_16x16x32_bf16(a1, bm, av[1][ct], 0, 0, 0);
            }
        }
        __builtin_amdgcn_s_setprio(0);
        // D: v[t = rt*16+4q+j][h = w*64+ct*16+l15] -> sVT[h][t]; zero pads t=20..31
#pragma unroll
        for (int ct = 0; ct < 4; ++ct) {
            int h = (w << 6) + ct * 16 + l15;
            {
                uint2 u2;
                u2.x = pk2(av[0][ct][0], av[0][ct][1]);
                u2.y = pk2(av[0][ct][2], av[0][ct][3]);
                *(uint2*)&sVT[h * TP + (q << 2)] = u2;
            }
            {
                uint2 u2;
                if (q == 0) {
                    u2.x = pk2(av[1][ct][0], av[1][ct][1]);
                    u2.y = pk2(av[1][ct][2], av[1][ct][3]);
                } else { u2.x = 0u; u2.y = 0u; }
                *(uint2*)&sVT[h * TP + 16 + (q << 2)] = u2;
            }
        }
    }
    BAR_LGKM();                            // B3: sVT + attnL + simE visible

    // ---- phase C: PV via MFMA + normalize-at-store ----
    {
        bf16x8 pa0 = __builtin_bit_cast(bf16x8, *(const uint4*)&attnL[l15 * 32 + (q << 3)]);
        bf16x8 pa1 = __builtin_bit_cast(bf16x8, *(const uint4*)&attnL[(16 + l15) * 32 + (q << 3)]);
        const f32x4 z = f32x4{0.f, 0.f, 0.f, 0.f};
        f32x4 o[2][4];
        __builtin_amdgcn_s_setprio(1);
#pragma unroll
        for (int ct = 0; ct < 4; ++ct) {
            bf16x8 pb = __builtin_bit_cast(bf16x8,
                *(const uint4*)&sVT[((w << 6) + ct * 16 + l15) * TP + (q << 3)]);
            o[0][ct] = __builtin_amdgcn_mfma_f32_16x16x32_bf16(pa0, pb, z, 0, 0, 0);
            o[1][ct] = __builtin_amdgcn_mfma_f32_16x16x32_bf16(pa1, pb, z, 0, 0, 0);
        }
        __builtin_amdgcn_s_setprio(0);
#pragma unroll
        for (int rt = 0; rt < 2; ++rt)
#pragma unroll
            for (int j = 0; j < 4; ++j) {
                int t = rt * 16 + (q << 2) + j;
                if (t < TT) {
                    int cnt = c_CNT[t], off = c_OFF[t];
                    float rs = (cnt == 0) ? 20.0f : s_simE[off];
#pragma unroll
                    for (int jj = 1; jj < 4; ++jj)
                        if (jj < cnt) rs += s_simE[off + jj];
                    float iv = __builtin_amdgcn_rcpf(rs);
                    float* op = outg + base + (size_t)t * CC + (w << 6) + l15;
#pragma unroll
                    for (int ct = 0; ct < 4; ++ct)
                        op[ct * 16] = o[rt][ct][j] * iv;
                }
            }
    }
}

extern "C" void kernel_launch(void* const* d_in, const int* in_sizes, int n_in,
                              void* d_out, int out_size, void* d_ws, size_t ws_size,
                              hipStream_t stream) {
    const float* feat1 = (const float*)d_in[0];
    const float* feat2 = (const float*)d_in[1];
    const float* Wq    = (const float*)d_in[2];
    const float* Wk    = (const float*)d_in[3];
    const float* Wv    = (const float*)d_in[4];
    uint16_t* mqkT = (uint16_t*)d_ws;          // 128 KB
    uint16_t* wvb  = mqkT + CC * CC;           // 128 KB
    uint16_t* BqS  = wvb  + CC * CC;           // 128 KB (fragment-ordered)
    uint16_t* BvS  = BqS  + CC * CC;           // 128 KB (fragment-ordered)

    prep1_kernel<<<CC, CC, 0, stream>>>(Wq, Wk, Wv, mqkT, wvb);
    prep2_kernel<<<64, NT, 0, stream>>>(mqkT, wvb, BqS, BvS);
    attn_main<<<NBATCH, NT, 0, stream>>>(feat1, feat2, BqS, BvS, (float*)d_out);
}

// Round 12
// 483.154 us; speedup vs baseline: 1.0046x; 1.0046x over previous
//
#include <hip/hip_runtime.h>
#include <stdint.h>

#define NBATCH 16384
#define TT     20
#define CC     256
#define FP     260   // f32 LDS row stride (1040B): rows shift 4 banks -> 2-way (free) on b128
#define FB     520   // bf16 row stride in u16 (in-place view of the same 1040B row slots)
#define LDK    264   // sT row stride (u16)
#define TP     40    // sVT inner stride (u16)
#define NT     256   // 4 waves

typedef __bf16 bf16x8 __attribute__((ext_vector_type(8)));
typedef float  f32x4  __attribute__((ext_vector_type(4)));

#define GLL16(g, l) __builtin_amdgcn_global_load_lds( \
    (const __attribute__((address_space(1))) uint32_t*)(g), \
    (__attribute__((address_space(3))) uint32_t*)(l), 16, 0, 0)

#define BAR_VM()   do { asm volatile("s_waitcnt vmcnt(0) lgkmcnt(0)" ::: "memory"); \
                        __builtin_amdgcn_s_barrier(); } while (0)
#define BAR_LGKM() do { asm volatile("s_waitcnt lgkmcnt(0)" ::: "memory"); \
                        __builtin_amdgcn_s_barrier(); } while (0)

// tb_mask tables: t=0,1:{0,1,2} t=2:{0,1,2,3} t=3..15:{t,t+1} t=16:uniform t=17..19:{17,18,19}
__constant__ int8_t c_CNT[TT] = {3,3,4,2,2,2,2,2,2,2,2,2,2,2,2,2,0,3,3,3};
__constant__ int8_t c_OFF[TT] = {0,3,6,10,12,14,16,18,20,22,24,26,28,30,32,34,0,36,39,42};
__constant__ int8_t c_PT[45]  = {0,0,0,1,1,1,2,2,2,2,3,3,4,4,5,5,6,6,7,7,8,8,9,9,
                                 10,10,11,11,12,12,13,13,14,14,15,15,17,17,17,18,18,18,19,19,19};
__constant__ int8_t c_PS[45]  = {0,1,2,0,1,2,0,1,2,3,3,4,4,5,5,6,6,7,7,8,8,9,9,10,
                                 10,11,11,12,12,13,13,14,14,15,15,16,17,18,19,17,18,19,17,18,19};

__device__ __forceinline__ uint16_t f2bf(float f) {
    __bf16 b = (__bf16)f;
    return __builtin_bit_cast(uint16_t, b);
}
__device__ __forceinline__ uint32_t pk2(float a, float b) {
    return (uint32_t)f2bf(a) | ((uint32_t)f2bf(b) << 16);
}
__device__ __forceinline__ float bflo(uint32_t u) { return __builtin_bit_cast(float, u << 16); }
__device__ __forceinline__ float bfhi(uint32_t u) { return __builtin_bit_cast(float, u & 0xffff0000u); }

// prep1: mqkT[n][k] = sum_h Wk[h,n]*Wq[h,k] / 16 ;  wvb[n][k] = bf16(Wv[n][k])
__global__ void prep1_kernel(const float* __restrict__ Wq, const float* __restrict__ Wk,
                             const float* __restrict__ Wv, uint16_t* __restrict__ mqkT,
                             uint16_t* __restrict__ wvb) {
    const int n = blockIdx.x;
    const int k = threadIdx.x;
    float acc = 0.f;
    for (int h = 0; h < CC; ++h)
        acc = fmaf(Wk[h * CC + n], Wq[h * CC + k], acc);
    mqkT[n * CC + k] = f2bf(acc * 0.0625f);
    wvb[n * CC + k]  = f2bf(Wv[n * CC + k]);
}

// prep2: swizzle tables into per-wave MFMA fragment order (one coalesced 1KB load per frag)
__global__ void prep2_kernel(const uint16_t* __restrict__ mqkT, const uint16_t* __restrict__ wvb,
                             uint16_t* __restrict__ BqS, uint16_t* __restrict__ BvS) {
    const int bid = blockIdx.x;          // 0..63 : m*32 + w*8 + kk
    const int m  = bid >> 5;
    const int w  = (bid >> 3) & 3;
    const int kk = bid & 7;
    const int ct   = threadIdx.x >> 6;
    const int lane = threadIdx.x & 63;
    const uint16_t* src = m ? wvb : mqkT;
    uint16_t*       dst = m ? BvS : BqS;
    const int n   = w * 64 + ct * 16 + (lane & 15);
    const int col = kk * 32 + ((lane >> 4) << 3);
    uint4 v = *(const uint4*)(src + n * CC + col);
    *(uint4*)(dst + ((size_t)((w * 32 + kk * 4 + ct) * 64 + lane) << 3)) = v;
}

// bf16 fragment: single b128 from in-place-converted row r, 8-elem unit u
__device__ __forceinline__ bf16x8 ldb(const uint16_t* __restrict__ s, int r, int u) {
    return __builtin_bit_cast(bf16x8, *(const uint4*)(s + r * FB + (u << 3)));
}

__global__ __launch_bounds__(NT, 3)
void attn_main(const float* __restrict__ f1g, const float* __restrict__ f2g,
               const uint16_t* __restrict__ BqS, const uint16_t* __restrict__ BvS,
               float* __restrict__ outg) {
    __shared__ char smem[54208];
    float*    sF1f  = (float*)smem;                   // feat1 f32 (20*1040B); bf16 in place
    float*    sF2f  = (float*)(smem + 20800);         // feat2 f32
    uint16_t* sT    = (uint16_t*)(smem + 41600);      // t1 bf16 [t][h], 10560B
    uint16_t* attnL = (uint16_t*)(smem + 52160);      // 32x32 exp-weights (rows 20+ = scratch)
    float*    s_simE = (float*)(smem + 52160 + 1280); // overlays attnL rows 20..25 (discarded D rows)
    uint16_t* sFb1 = (uint16_t*)sF1f;                 // bf16 view, stride FB
    uint16_t* sFb2 = (uint16_t*)sF2f;
    uint16_t* sVT  = (uint16_t*)smem;                 // v^T [256][TP] overlays sF1 after B2

    const int tid  = threadIdx.x;
    const int lane = tid & 63;
    const int w    = tid >> 6;             // wave owns 64 hid cols
    const int l15  = lane & 15;
    const int q    = lane >> 4;
    const size_t base = (size_t)blockIdx.x * TT * CC;
    const float* f1 = f1g + base;
    const float* f2 = f2g + base;

    // ---- stage: async DMA fp32 rows -> LDS (zero VGPR, zero VALU) ----
#pragma unroll
    for (int j = 0; j < 5; ++j) {
        int r = w * 5 + j;
        GLL16(f1 + r * 256 + (lane << 2), sF1f + r * FP);
        GLL16(f2 + r * 256 + (lane << 2), sF2f + r * FP);
    }
    {   // attnL prefill rows 0..19 only: zeros; row16 cols0..19 = 1.0 (uniform-row trick).
        // Rows 20..31 untouched: they feed only D rows >= 20, which are discarded.
        uint32_t* aL = (uint32_t*)attnL;
#pragma unroll
        for (int rep = 0; rep < 2; ++rep) {
            int s = tid + (rep << 8);
            if (s < 320)
                aL[s] = ((s >> 4) == 16 && (s & 15) < 10) ? 0x3F803F80u : 0u;
        }
    }
    BAR_VM();                              // B1: DMA complete

    // ---- convert-once: f32 -> bf16 in place; wave-owned rows => no cross-wave hazard ----
#pragma unroll
    for (int j = 0; j < 5; ++j) {
        int r = w * 5 + j;
        float4 v1 = *(const float4*)(sF1f + r * FP + (lane << 2));
        float4 v2 = *(const float4*)(sF2f + r * FP + (lane << 2));
        uint2 u1; u1.x = pk2(v1.x, v1.y); u1.y = pk2(v1.z, v1.w);
        uint2 u2; u2.x = pk2(v2.x, v2.y); u2.y = pk2(v2.z, v2.w);
        *(uint2*)(sFb1 + r * FB + (lane << 2)) = u1;
        *(uint2*)(sFb2 + r * FB + (lane << 2)) = u2;
    }
    BAR_LGKM();                            // B1.5: bf16 tiles visible

    const uint16_t* bq = BqS + ((size_t)w << 14);
    const uint16_t* bv = BvS + ((size_t)w << 14);
    const int rB0 = l15;
    const int rB1 = (16 + l15 < TT) ? 16 + l15 : TT - 1;

    // ---- phase A: GEMM1 swapped (A=Mqk frags, B=feat1^T) -> t1^T -> sT ----
    {
        f32x4 acc[4][2];
#pragma unroll
        for (int mt = 0; mt < 4; ++mt)
#pragma unroll
            for (int ct = 0; ct < 2; ++ct)
                acc[mt][ct] = f32x4{0.f, 0.f, 0.f, 0.f};
        __builtin_amdgcn_s_setprio(1);
#pragma unroll
        for (int kk = 0; kk < 8; ++kk) {
            const int u = (kk << 2) + q;
            bf16x8 b0 = ldb(sFb1, rB0, u);
            bf16x8 b1 = ldb(sFb1, rB1, u);
#pragma unroll
            for (int mt = 0; mt < 4; ++mt) {
                bf16x8 am = __builtin_bit_cast(bf16x8,
                    *(const uint4*)(bq + (((kk << 2) + mt) * 64 + lane) * 8));
                acc[mt][0] = __builtin_amdgcn_mfma_f32_16x16x32_bf16(am, b0, acc[mt][0], 0, 0, 0);
                acc[mt][1] = __builtin_amdgcn_mfma_f32_16x16x32_bf16(am, b1, acc[mt][1], 0, 0, 0);
            }
        }
        __builtin_amdgcn_s_setprio(0);
        // D: lane holds t1^T[h = w*64+mt*16+4q+j][t = ct*16+l15] -> sT[t][h]
#pragma unroll
        for (int mt = 0; mt < 4; ++mt)
#pragma unroll
            for (int ct = 0; ct < 2; ++ct) {
                int t = ct * 16 + l15;
                if (t < TT) {
                    int h0 = (w << 6) + mt * 16 + (q << 2);
                    uint2 u2;
                    u2.x = pk2(acc[mt][ct][0], acc[mt][ct][1]);
                    u2.y = pk2(acc[mt][ct][2], acc[mt][ct][3]);
                    *(uint2*)&sT[t * LDK + h0] = u2;
                }
            }
    }
    BAR_LGKM();                            // B2: sT visible; sFb1 reads done

    // ---- phase B: sim+exp (180 thr) and GEMM2 -> sVT (overlays sF1 region) ----
    if (tid < 180) {
        int d = tid >> 2;
        int p = tid & 3;
        int t = c_PT[d], s = c_PS[d];
        const uint16_t* ap = sT + t * LDK + (p << 3);
        const uint16_t* bp = sFb2 + s * FB + (p << 3);
        float da = 0.f;
#pragma unroll
        for (int c = 0; c < 256; c += 32) {   // h = p*8 + c .. +8
            uint4 ua = *(const uint4*)(ap + c);
            uint4 ub = *(const uint4*)(bp + c);
            da = fmaf(bflo(ua.x), bflo(ub.x), da);
            da = fmaf(bfhi(ua.x), bfhi(ub.x), da);
            da = fmaf(bflo(ua.y), bflo(ub.y), da);
            da = fmaf(bfhi(ua.y), bfhi(ub.y), da);
            da = fmaf(bflo(ua.z), bflo(ub.z), da);
            da = fmaf(bfhi(ua.z), bfhi(ub.z), da);
            da = fmaf(bflo(ua.w), bflo(ub.w), da);
            da = fmaf(bfhi(ua.w), bfhi(ub.w), da);
        }
        da += __shfl_xor(da, 1);
        da += __shfl_xor(da, 2);
        if (p == 0) {
            float e = __expf(da);
            attnL[t * 32 + s] = f2bf(e);
            s_simE[d] = e;
        }
    }
    {
        f32x4 av[2][4];
#pragma unroll
        for (int rt = 0; rt < 2; ++rt)
#pragma unroll
            for (int ct = 0; ct < 4; ++ct)
                av[rt][ct] = f32x4{0.f, 0.f, 0.f, 0.f};
        __builtin_amdgcn_s_setprio(1);
#pragma unroll
        for (int kk = 0; kk < 8; ++kk) {
            const int u = (kk << 2) + q;
            bf16x8 a0 = ldb(sFb2, rB0, u);
            bf16x8 a1 = ldb(sFb2, rB1, u);
#pragma unroll
            for (int ct = 0; ct < 4; ++ct) {
                bf16x8 bm = __builtin_bit_cast(bf16x8,
                    *(const uint4*)(bv + (((kk << 2) + ct) * 64 + lane) * 8));
                av[0][ct] = __builtin_amdgcn_mfma_f32_16x16x32_bf16(a0, bm, av[0][ct], 0, 0, 0);
                av[1][ct] = __builtin_amdgcn_mfma_f32_16x16x32_bf16(a1, bm, av[1][ct], 0, 0, 0);
            }
        }
        __builtin_amdgcn_s_setprio(0);
        // D: v[t = rt*16+4q+j][h = w*64+ct*16+l15] -> sVT[h][t]; zero pads t=20..31
#pragma unroll
        for (int ct = 0; ct < 4; ++ct) {
            int h = (w << 6) + ct * 16 + l15;
            {
                uint2 u2;
                u2.x = pk2(av[0][ct][0], av[0][ct][1]);
                u2.y = pk2(av[0][ct][2], av[0][ct][3]);
                *(uint2*)&sVT[h * TP + (q << 2)] = u2;
            }
            {
                uint2 u2;
                if (q == 0) {
                    u2.x = pk2(av[1][ct][0], av[1][ct][1]);
                    u2.y = pk2(av[1][ct][2], av[1][ct][3]);
                } else { u2.x = 0u; u2.y = 0u; }
                *(uint2*)&sVT[h * TP + 16 + (q << 2)] = u2;
            }
        }
    }
    BAR_LGKM();                            // B3: sVT + attnL + simE visible

    // ---- phase C: PV via MFMA + normalize-at-store ----
    {
        bf16x8 pa0 = __builtin_bit_cast(bf16x8, *(const uint4*)&attnL[l15 * 32 + (q << 3)]);
        bf16x8 pa1 = __builtin_bit_cast(bf16x8, *(const uint4*)&attnL[(16 + l15) * 32 + (q << 3)]);
        const f32x4 z = f32x4{0.f, 0.f, 0.f, 0.f};
        f32x4 o[2][4];
        __builtin_amdgcn_s_setprio(1);
#pragma unroll
        for (int ct = 0; ct < 4; ++ct) {
            bf16x8 pb = __builtin_bit_cast(bf16x8,
                *(const uint4*)&sVT[((w << 6) + ct * 16 + l15) * TP + (q << 3)]);
            o[0][ct] = __builtin_amdgcn_mfma_f32_16x16x32_bf16(pa0, pb, z, 0, 0, 0);
            o[1][ct] = __builtin_amdgcn_mfma_f32_16x16x32_bf16(pa1, pb, z, 0, 0, 0);
        }
        __builtin_amdgcn_s_setprio(0);
#pragma unroll
        for (int rt = 0; rt < 2; ++rt)
#pragma unroll
            for (int j = 0; j < 4; ++j) {
                int t = rt * 16 + (q << 2) + j;
                if (t < TT) {
                    int cnt = c_CNT[t], off = c_OFF[t];
                    float rs = (cnt == 0) ? 20.0f : s_simE[off];
#pragma unroll
                    for (int jj = 1; jj < 4; ++jj)
                        if (jj < cnt) rs += s_simE[off + jj];
                    float iv = __builtin_amdgcn_rcpf(rs);
                    float* op = outg + base + (size_t)t * CC + (w << 6) + l15;
#pragma unroll
                    for (int ct = 0; ct < 4; ++ct)
                        op[ct * 16] = o[rt][ct][j] * iv;
                }
            }
    }
}

extern "C" void kernel_launch(void* const* d_in, const int* in_sizes, int n_in,
                              void* d_out, int out_size, void* d_ws, size_t ws_size,
                              hipStream_t stream) {
    const float* feat1 = (const float*)d_in[0];
    const float* feat2 = (const float*)d_in[1];
    const float* Wq    = (const float*)d_in[2];
    const float* Wk    = (const float*)d_in[3];
    const float* Wv    = (const float*)d_in[4];
    uint16_t* mqkT = (uint16_t*)d_ws;          // 128 KB
    uint16_t* wvb  = mqkT + CC * CC;           // 128 KB
    uint16_t* BqS  = wvb  + CC * CC;           // 128 KB (fragment-ordered)
    uint16_t* BvS  = BqS  + CC * CC;           // 128 KB (fragment-ordered)

    prep1_kernel<<<CC, CC, 0, stream>>>(Wq, Wk, Wv, mqkT, wvb);
    prep2_kernel<<<64, NT, 0, stream>>>(mqkT, wvb, BqS, BvS);
    attn_main<<<NBATCH, NT, 0, stream>>>(feat1, feat2, BqS, BvS, (float*)d_out);
}

// Round 13
// 384.056 us; speedup vs baseline: 1.2638x; 1.2580x over previous
//
#include <hip/hip_runtime.h>
#include <stdint.h>

#define NBATCH 16384
#define TT     20
#define CC     256
#define FP     260   // f32 LDS row stride (1040B): rows shift 4 banks -> 2-way (free) on b128
#define FB     520   // bf16 row stride in u16 (in-place view of the same 1040B row slots)
#define LDK    264   // sT row stride (u16): 528B = 33*16B (aligned b128 rows)
#define TP     40    // sVT inner stride (u16)
#define NT     256   // 4 waves

typedef __bf16 bf16x8 __attribute__((ext_vector_type(8)));
typedef float  f32x4  __attribute__((ext_vector_type(4)));

#define GLL16(g, l) __builtin_amdgcn_global_load_lds( \
    (const __attribute__((address_space(1))) uint32_t*)(g), \
    (__attribute__((address_space(3))) uint32_t*)(l), 16, 0, 0)

#define BAR_VM()   do { asm volatile("s_waitcnt vmcnt(0) lgkmcnt(0)" ::: "memory"); \
                        __builtin_amdgcn_s_barrier(); } while (0)
#define BAR_LGKM() do { asm volatile("s_waitcnt lgkmcnt(0)" ::: "memory"); \
                        __builtin_amdgcn_s_barrier(); } while (0)

// tb_mask tables: t=0,1:{0,1,2} t=2:{0,1,2,3} t=3..15:{t,t+1} t=16:uniform t=17..19:{17,18,19}
__constant__ int8_t c_CNT[TT] = {3,3,4,2,2,2,2,2,2,2,2,2,2,2,2,2,0,3,3,3};
__constant__ int8_t c_OFF[TT] = {0,3,6,10,12,14,16,18,20,22,24,26,28,30,32,34,0,36,39,42};
__constant__ int8_t c_PT[45]  = {0,0,0,1,1,1,2,2,2,2,3,3,4,4,5,5,6,6,7,7,8,8,9,9,
                                 10,10,11,11,12,12,13,13,14,14,15,15,17,17,17,18,18,18,19,19,19};
__constant__ int8_t c_PS[45]  = {0,1,2,0,1,2,0,1,2,3,3,4,4,5,5,6,6,7,7,8,8,9,9,10,
                                 10,11,11,12,12,13,13,14,14,15,15,16,17,18,19,17,18,19,17,18,19};

__device__ __forceinline__ uint16_t f2bf(float f) {
    __bf16 b = (__bf16)f;
    return __builtin_bit_cast(uint16_t, b);
}
__device__ __forceinline__ uint32_t pk2(float a, float b) {
    return (uint32_t)f2bf(a) | ((uint32_t)f2bf(b) << 16);
}
__device__ __forceinline__ float bflo(uint32_t u) { return __builtin_bit_cast(float, u << 16); }
__device__ __forceinline__ float bfhi(uint32_t u) { return __builtin_bit_cast(float, u & 0xffff0000u); }

// prep1: mqkT[n][k] = sum_h Wk[h,n]*Wq[h,k] / 16 ;  wvb[n][k] = bf16(Wv[n][k])
__global__ void prep1_kernel(const float* __restrict__ Wq, const float* __restrict__ Wk,
                             const float* __restrict__ Wv, uint16_t* __restrict__ mqkT,
                             uint16_t* __restrict__ wvb) {
    const int n = blockIdx.x;
    const int k = threadIdx.x;
    float acc = 0.f;
    for (int h = 0; h < CC; ++h)
        acc = fmaf(Wk[h * CC + n], Wq[h * CC + k], acc);
    mqkT[n * CC + k] = f2bf(acc * 0.0625f);
    wvb[n * CC + k]  = f2bf(Wv[n * CC + k]);
}

// prep2: swizzle tables into per-wave MFMA fragment order (one coalesced 1KB load per frag)
__global__ void prep2_kernel(const uint16_t* __restrict__ mqkT, const uint16_t* __restrict__ wvb,
                             uint16_t* __restrict__ BqS, uint16_t* __restrict__ BvS) {
    const int bid = blockIdx.x;          // 0..63 : m*32 + w*8 + kk
    const int m  = bid >> 5;
    const int w  = (bid >> 3) & 3;
    const int kk = bid & 7;
    const int ct   = threadIdx.x >> 6;
    const int lane = threadIdx.x & 63;
    const uint16_t* src = m ? wvb : mqkT;
    uint16_t*       dst = m ? BvS : BqS;
    const int n   = w * 64 + ct * 16 + (lane & 15);
    const int col = kk * 32 + ((lane >> 4) << 3);
    uint4 v = *(const uint4*)(src + n * CC + col);
    *(uint4*)(dst + ((size_t)((w * 32 + kk * 4 + ct) * 64 + lane) << 3)) = v;
}

// bf16 fragment: single b128 from in-place-converted row r, 8-elem unit u
__device__ __forceinline__ bf16x8 ldb(const uint16_t* __restrict__ s, int r, int u) {
    return __builtin_bit_cast(bf16x8, *(const uint4*)(s + r * FB + (u << 3)));
}

__global__ __launch_bounds__(NT, 3)
void attn_main(const float* __restrict__ f1g, const float* __restrict__ f2g,
               const uint16_t* __restrict__ BqS, const uint16_t* __restrict__ BvS,
               float* __restrict__ outg) {
    // 53632 B total -> allocates 53760 (empirically 3 blocks/CU; r9 proved this value fits 3x)
    __shared__ char smem[53632];
    float*    sF1f  = (float*)smem;                   // feat1 f32 (20*1040B); bf16 in place
    float*    sF2f  = (float*)(smem + 20800);         // feat2 f32
    uint16_t* attnL = (uint16_t*)(smem + 41600);      // [20][32] exp-weights; PV reads of rows
                                                      // 20..31 spill into simE/sT bytes (in-bounds
                                                      // garbage -> only discarded D rows 20..31)
    float*    s_simE = (float*)(smem + 42880);        // 45 f32
    uint16_t* sT    = (uint16_t*)(smem + 43072);      // t1 bf16 [20][264], 10560B, ends 53632
    uint16_t* sFb1 = (uint16_t*)sF1f;                 // bf16 view, stride FB
    uint16_t* sFb2 = (uint16_t*)sF2f;
    uint16_t* sVT  = (uint16_t*)smem;                 // v^T [256][TP] overlays sF1 after B2

    const int tid  = threadIdx.x;
    const int lane = tid & 63;
    const int w    = tid >> 6;             // wave owns 64 hid cols
    const int l15  = lane & 15;
    const int q    = lane >> 4;
    const size_t base = (size_t)blockIdx.x * TT * CC;
    const float* f1 = f1g + base;
    const float* f2 = f2g + base;

    // ---- stage: async DMA fp32 rows -> LDS (zero VGPR, zero VALU) ----
#pragma unroll
    for (int j = 0; j < 5; ++j) {
        int r = w * 5 + j;
        GLL16(f1 + r * 256 + (lane << 2), sF1f + r * FP);
        GLL16(f2 + r * 256 + (lane << 2), sF2f + r * FP);
    }
    {   // attnL prefill (all 20 valid rows x 32 cols): zeros; row16 cols0..19 = 1.0
        uint32_t* aL = (uint32_t*)attnL;
#pragma unroll
        for (int rep = 0; rep < 2; ++rep) {
            int s = tid + (rep << 8);
            if (s < 320)
                aL[s] = ((s >> 4) == 16 && (s & 15) < 10) ? 0x3F803F80u : 0u;
        }
    }
    BAR_VM();                              // B1: DMA complete

    // ---- convert-once: f32 -> bf16 in place; wave-owned rows => no cross-wave hazard ----
#pragma unroll
    for (int j = 0; j < 5; ++j) {
        int r = w * 5 + j;
        float4 v1 = *(const float4*)(sF1f + r * FP + (lane << 2));
        float4 v2 = *(const float4*)(sF2f + r * FP + (lane << 2));
        uint2 u1; u1.x = pk2(v1.x, v1.y); u1.y = pk2(v1.z, v1.w);
        uint2 u2; u2.x = pk2(v2.x, v2.y); u2.y = pk2(v2.z, v2.w);
        *(uint2*)(sFb1 + r * FB + (lane << 2)) = u1;
        *(uint2*)(sFb2 + r * FB + (lane << 2)) = u2;
    }
    BAR_LGKM();                            // B1.5: bf16 tiles visible

    const uint16_t* bq = BqS + ((size_t)w << 14);
    const uint16_t* bv = BvS + ((size_t)w << 14);
    const int rB0 = l15;
    const int rB1 = (16 + l15 < TT) ? 16 + l15 : TT - 1;

    // ---- phase A: GEMM1 swapped (A=Mqk frags, B=feat1^T) -> t1^T -> sT ----
    {
        f32x4 acc[4][2];
#pragma unroll
        for (int mt = 0; mt < 4; ++mt)
#pragma unroll
            for (int ct = 0; ct < 2; ++ct)
                acc[mt][ct] = f32x4{0.f, 0.f, 0.f, 0.f};
        __builtin_amdgcn_s_setprio(1);
#pragma unroll
        for (int kk = 0; kk < 8; ++kk) {
            const int u = (kk << 2) + q;
            bf16x8 b0 = ldb(sFb1, rB0, u);
            bf16x8 b1 = ldb(sFb1, rB1, u);
#pragma unroll
            for (int mt = 0; mt < 4; ++mt) {
                bf16x8 am = __builtin_bit_cast(bf16x8,
                    *(const uint4*)(bq + (((kk << 2) + mt) * 64 + lane) * 8));
                acc[mt][0] = __builtin_amdgcn_mfma_f32_16x16x32_bf16(am, b0, acc[mt][0], 0, 0, 0);
                acc[mt][1] = __builtin_amdgcn_mfma_f32_16x16x32_bf16(am, b1, acc[mt][1], 0, 0, 0);
            }
        }
        __builtin_amdgcn_s_setprio(0);
        // D: lane holds t1^T[h = w*64+mt*16+4q+j][t = ct*16+l15] -> sT[t][h]
#pragma unroll
        for (int mt = 0; mt < 4; ++mt)
#pragma unroll
            for (int ct = 0; ct < 2; ++ct) {
                int t = ct * 16 + l15;
                if (t < TT) {
                    int h0 = (w << 6) + mt * 16 + (q << 2);
                    uint2 u2;
                    u2.x = pk2(acc[mt][ct][0], acc[mt][ct][1]);
                    u2.y = pk2(acc[mt][ct][2], acc[mt][ct][3]);
                    *(uint2*)&sT[t * LDK + h0] = u2;
                }
            }
    }
    BAR_LGKM();                            // B2: sT visible; sFb1 reads done

    // ---- phase B: sim+exp (180 thr) and GEMM2 -> sVT (overlays sF1 region) ----
    if (tid < 180) {
        int d = tid >> 2;
        int p = tid & 3;
        int t = c_PT[d], s = c_PS[d];
        const uint16_t* ap = sT + t * LDK + (p << 3);
        const uint16_t* bp = sFb2 + s * FB + (p << 3);
        float da = 0.f;
#pragma unroll
        for (int c = 0; c < 256; c += 32) {   // h = p*8 + c .. +8
            uint4 ua = *(const uint4*)(ap + c);
            uint4 ub = *(const uint4*)(bp + c);
            da = fmaf(bflo(ua.x), bflo(ub.x), da);
            da = fmaf(bfhi(ua.x), bfhi(ub.x), da);
            da = fmaf(bflo(ua.y), bflo(ub.y), da);
            da = fmaf(bfhi(ua.y), bfhi(ub.y), da);
            da = fmaf(bflo(ua.z), bflo(ub.z), da);
            da = fmaf(bfhi(ua.z), bfhi(ub.z), da);
            da = fmaf(bflo(ua.w), bflo(ub.w), da);
            da = fmaf(bfhi(ua.w), bfhi(ub.w), da);
        }
        da += __shfl_xor(da, 1);
        da += __shfl_xor(da, 2);
        if (p == 0) {
            float e = __expf(da);
            attnL[t * 32 + s] = f2bf(e);
            s_simE[d] = e;
        }
    }
    {
        f32x4 av[2][4];
#pragma unroll
        for (int rt = 0; rt < 2; ++rt)
#pragma unroll
            for (int ct = 0; ct < 4; ++ct)
                av[rt][ct] = f32x4{0.f, 0.f, 0.f, 0.f};
        __builtin_amdgcn_s_setprio(1);
#pragma unroll
        for (int kk = 0; kk < 8; ++kk) {
            const int u = (kk << 2) + q;
            bf16x8 a0 = ldb(sFb2, rB0, u);
            bf16x8 a1 = ldb(sFb2, rB1, u);
#pragma unroll
            for (int ct = 0; ct < 4; ++ct) {
                bf16x8 bm = __builtin_bit_cast(bf16x8,
                    *(const uint4*)(bv + (((kk << 2) + ct) * 64 + lane) * 8));
                av[0][ct] = __builtin_amdgcn_mfma_f32_16x16x32_bf16(a0, bm, av[0][ct], 0, 0, 0);
                av[1][ct] = __builtin_amdgcn_mfma_f32_16x16x32_bf16(a1, bm, av[1][ct], 0, 0, 0);
            }
        }
        __builtin_amdgcn_s_setprio(0);
        // D: v[t = rt*16+4q+j][h = w*64+ct*16+l15] -> sVT[h][t]; zero pads t=20..31
#pragma unroll
        for (int ct = 0; ct < 4; ++ct) {
            int h = (w << 6) + ct * 16 + l15;
            {
                uint2 u2;
                u2.x = pk2(av[0][ct][0], av[0][ct][1]);
                u2.y = pk2(av[0][ct][2], av[0][ct][3]);
                *(uint2*)&sVT[h * TP + (q << 2)] = u2;
            }
            {
                uint2 u2;
                if (q == 0) {
                    u2.x = pk2(av[1][ct][0], av[1][ct][1]);
                    u2.y = pk2(av[1][ct][2], av[1][ct][3]);
                } else { u2.x = 0u; u2.y = 0u; }
                *(uint2*)&sVT[h * TP + 16 + (q << 2)] = u2;
            }
        }
    }
    BAR_LGKM();                            // B3: sVT + attnL + simE visible

    // ---- phase C: PV via MFMA + normalize-at-store ----
    {
        bf16x8 pa0 = __builtin_bit_cast(bf16x8, *(const uint4*)&attnL[l15 * 32 + (q << 3)]);
        bf16x8 pa1 = __builtin_bit_cast(bf16x8, *(const uint4*)&attnL[(16 + l15) * 32 + (q << 3)]);
        const f32x4 z = f32x4{0.f, 0.f, 0.f, 0.f};
        f32x4 o[2][4];
        __builtin_amdgcn_s_setprio(1);
#pragma unroll
        for (int ct = 0; ct < 4; ++ct) {
            bf16x8 pb = __builtin_bit_cast(bf16x8,
                *(const uint4*)&sVT[((w << 6) + ct * 16 + l15) * TP + (q << 3)]);
            o[0][ct] = __builtin_amdgcn_mfma_f32_16x16x32_bf16(pa0, pb, z, 0, 0, 0);
            o[1][ct] = __builtin_amdgcn_mfma_f32_16x16x32_bf16(pa1, pb, z, 0, 0, 0);
        }
        __builtin_amdgcn_s_setprio(0);
#pragma unroll
        for (int rt = 0; rt < 2; ++rt)
#pragma unroll
            for (int j = 0; j < 4; ++j) {
                int t = rt * 16 + (q << 2) + j;
                if (t < TT) {
                    int cnt = c_CNT[t], off = c_OFF[t];
                    float rs = (cnt == 0) ? 20.0f : s_simE[off];
#pragma unroll
                    for (int jj = 1; jj < 4; ++jj)
                        if (jj < cnt) rs += s_simE[off + jj];
                    float iv = __builtin_amdgcn_rcpf(rs);
                    float* op = outg + base + (size_t)t * CC + (w << 6) + l15;
#pragma unroll
                    for (int ct = 0; ct < 4; ++ct)
                        op[ct * 16] = o[rt][ct][j] * iv;
                }
            }
    }
}

extern "C" void kernel_launch(void* const* d_in, const int* in_sizes, int n_in,
                              void* d_out, int out_size, void* d_ws, size_t ws_size,
                              hipStream_t stream) {
    const float* feat1 = (const float*)d_in[0];
    const float* feat2 = (const float*)d_in[1];
    const float* Wq    = (const float*)d_in[2];
    const float* Wk    = (const float*)d_in[3];
    const float* Wv    = (const float*)d_in[4];
    uint16_t* mqkT = (uint16_t*)d_ws;          // 128 KB
    uint16_t* wvb  = mqkT + CC * CC;           // 128 KB
    uint16_t* BqS  = wvb  + CC * CC;           // 128 KB (fragment-ordered)
    uint16_t* BvS  = BqS  + CC * CC;           // 128 KB (fragment-ordered)

    prep1_kernel<<<CC, CC, 0, stream>>>(Wq, Wk, Wv, mqkT, wvb);
    prep2_kernel<<<64, NT, 0, stream>>>(mqkT, wvb, BqS, BvS);
    attn_main<<<NBATCH, NT, 0, stream>>>(feat1, feat2, BqS, BvS, (float*)d_out);
}